// Round 1
// baseline (587.173 us; speedup 1.0000x reference)
//
#include <hip/hip_runtime.h>
#include <hip/hip_bf16.h>

typedef short short8 __attribute__((ext_vector_type(8)));
typedef float f32x4  __attribute__((ext_vector_type(4)));

#define EMB  512
#define MEM  128
#define G3   384
#define BR   64
#define NTHR 512

__device__ __forceinline__ short f2b(float f) {
  unsigned u = __float_as_uint(f);
  u += 0x7fffu + ((u >> 16) & 1u);          // RNE; inputs are finite
  return (short)(u >> 16);
}
__device__ __forceinline__ float b2f(short s) {
  return __uint_as_float(((unsigned)(unsigned short)s) << 16);
}
__device__ __forceinline__ float sigm(float x)     { return 1.f / (1.f + __expf(-x)); }
__device__ __forceinline__ float tanhfast(float x) { return 2.f / (1.f + __expf(-2.f * x)) - 1.f; }

// ---- convert W_ih / W_hh to bf16 in workspace ----
__global__ void prep_w_kernel(const float* __restrict__ wih, const float* __restrict__ whh,
                              short* __restrict__ outw) {
  int i = blockIdx.x * blockDim.x + threadIdx.x;
  const int n1 = G3 * EMB, n2 = G3 * MEM;
  if (i < n1) outw[i] = f2b(wih[i]);
  else if (i < n1 + n2) outw[i] = f2b(whh[i - n1]);
}

// ---- full bank copy (scatter kernel overwrites active rows afterwards) ----
__global__ void copy_bank_kernel(const f32x4* __restrict__ src, f32x4* __restrict__ dst, int n4) {
  int i = blockIdx.x * blockDim.x + threadIdx.x;
  int stride = gridDim.x * blockDim.x;
  for (; i < n4; i += stride) dst[i] = src[i];
}

template <bool BF16W>
__global__ __launch_bounds__(NTHR, 2)
void fused_gru_kernel(const float* __restrict__ emb, const int* __restrict__ ids,
                      const float* __restrict__ bank,
                      const float* __restrict__ Wihf, const float* __restrict__ Whhf,
                      const float* __restrict__ bih,  const float* __restrict__ bhh,
                      const float* __restrict__ Wcls, const float* __restrict__ bcls,
                      const short* __restrict__ Wihb, const short* __restrict__ Whhb,
                      float* __restrict__ out_logits, float* __restrict__ out_bank, int N) {
  __shared__ short sX[BR * EMB];      // bf16 bits, XOR-swizzled, 64 KB
  __shared__ short sH[BR * MEM];      // 16 KB
  __shared__ float sLP[4][BR][2];     // logits mem-part partials, 2 KB

  const int t  = threadIdx.x;
  const int r0 = blockIdx.x * BR;

  // ---------------- stage X (f32 -> bf16, swizzled) ----------------
  {
    const int row  = t >> 3;
    int grow = r0 + row; if (grow > N - 1) grow = N - 1;
    const float* xs = emb + (size_t)grow * EMB;
    const int p = t & 7;
#pragma unroll
    for (int i = 0; i < 8; ++i) {
      const int k8 = p + i * 8;
      const int k  = k8 * 8;
      f32x4 a = *(const f32x4*)(xs + k);
      f32x4 b = *(const f32x4*)(xs + k + 4);
      short8 v;
      v[0] = f2b(a[0]); v[1] = f2b(a[1]); v[2] = f2b(a[2]); v[3] = f2b(a[3]);
      v[4] = f2b(b[0]); v[5] = f2b(b[1]); v[6] = f2b(b[2]); v[7] = f2b(b[3]);
      const int byte = (row * (EMB * 2) + k8 * 16) ^ ((row & 7) << 4);
      *(short8*)((char*)sX + byte) = v;
    }
  }
  // ---------------- stage H (gathered memory rows) ----------------
  {
#pragma unroll
    for (int it = 0; it < 2; ++it) {
      const int gi  = t + it * NTHR;      // 0..1023
      const int row = gi >> 4;
      const int k   = (gi & 15) * 8;
      int grow = r0 + row; if (grow > N - 1) grow = N - 1;
      const int gid = ids[grow];
      const float* hs = bank + (size_t)gid * MEM + k;
      f32x4 a = *(const f32x4*)hs;
      f32x4 b = *(const f32x4*)(hs + 4);
      short8 v;
      v[0] = f2b(a[0]); v[1] = f2b(a[1]); v[2] = f2b(a[2]); v[3] = f2b(a[3]);
      v[4] = f2b(b[0]); v[5] = f2b(b[1]); v[6] = f2b(b[2]); v[7] = f2b(b[3]);
      const int byte = (row * (MEM * 2) + k * 2) ^ ((row & 7) << 4);
      *(short8*)((char*)sH + byte) = v;
    }
  }
  __syncthreads();

  const int w     = t >> 6;
  const int l     = t & 63;
  const int lr    = l & 15;
  const int lk    = l >> 4;
  const int rbase = (w >> 2) * 32;    // 0 or 32
  const int mbase = (w & 3) * 32;     // 0,32,64,96

  f32x4 accI[2][2][3];                // [rowtile][mtile][gate]
  f32x4 accH[2][2][3];
  const f32x4 zero = {0.f, 0.f, 0.f, 0.f};
#pragma unroll
  for (int rt = 0; rt < 2; ++rt)
#pragma unroll
    for (int mt = 0; mt < 2; ++mt)
#pragma unroll
      for (int g = 0; g < 3; ++g) { accI[rt][mt][g] = zero; accH[rt][mt][g] = zero; }

  // ---------------- GEMM1: gi = X @ W_ih^T ----------------
  for (int kc = 0; kc < EMB / 32; ++kc) {
    const int k0 = kc * 32;
    short8 a0, a1;
    {
      int row  = rbase + lr;
      int byte = (row * (EMB * 2) + (k0 + lk * 8) * 2) ^ ((row & 7) << 4);
      a0 = *(short8*)((char*)sX + byte);
      row += 16;
      byte = (row * (EMB * 2) + (k0 + lk * 8) * 2) ^ ((row & 7) << 4);
      a1 = *(short8*)((char*)sX + byte);
    }
#pragma unroll
    for (int g = 0; g < 3; ++g)
#pragma unroll
      for (int mt = 0; mt < 2; ++mt) {
        const int c = g * MEM + mbase + mt * 16 + lr;
        short8 bq;
        if constexpr (BF16W) {
          bq = *(const short8*)(Wihb + (size_t)c * EMB + k0 + lk * 8);
        } else {
          const float* wp = Wihf + (size_t)c * EMB + k0 + lk * 8;
          f32x4 wa = *(const f32x4*)wp, wb = *(const f32x4*)(wp + 4);
          bq[0] = f2b(wa[0]); bq[1] = f2b(wa[1]); bq[2] = f2b(wa[2]); bq[3] = f2b(wa[3]);
          bq[4] = f2b(wb[0]); bq[5] = f2b(wb[1]); bq[6] = f2b(wb[2]); bq[7] = f2b(wb[3]);
        }
        accI[0][mt][g] = __builtin_amdgcn_mfma_f32_16x16x32_bf16(a0, bq, accI[0][mt][g], 0, 0, 0);
        accI[1][mt][g] = __builtin_amdgcn_mfma_f32_16x16x32_bf16(a1, bq, accI[1][mt][g], 0, 0, 0);
      }
  }
  // ---------------- GEMM2: gh = H @ W_hh^T ----------------
  for (int kc = 0; kc < MEM / 32; ++kc) {
    const int k0 = kc * 32;
    short8 a0, a1;
    {
      int row  = rbase + lr;
      int byte = (row * (MEM * 2) + (k0 + lk * 8) * 2) ^ ((row & 7) << 4);
      a0 = *(short8*)((char*)sH + byte);
      row += 16;
      byte = (row * (MEM * 2) + (k0 + lk * 8) * 2) ^ ((row & 7) << 4);
      a1 = *(short8*)((char*)sH + byte);
    }
#pragma unroll
    for (int g = 0; g < 3; ++g)
#pragma unroll
      for (int mt = 0; mt < 2; ++mt) {
        const int c = g * MEM + mbase + mt * 16 + lr;
        short8 bq;
        if constexpr (BF16W) {
          bq = *(const short8*)(Whhb + (size_t)c * MEM + k0 + lk * 8);
        } else {
          const float* wp = Whhf + (size_t)c * MEM + k0 + lk * 8;
          f32x4 wa = *(const f32x4*)wp, wb = *(const f32x4*)(wp + 4);
          bq[0] = f2b(wa[0]); bq[1] = f2b(wa[1]); bq[2] = f2b(wa[2]); bq[3] = f2b(wa[3]);
          bq[4] = f2b(wb[0]); bq[5] = f2b(wb[1]); bq[6] = f2b(wb[2]); bq[7] = f2b(wb[3]);
        }
        accH[0][mt][g] = __builtin_amdgcn_mfma_f32_16x16x32_bf16(a0, bq, accH[0][mt][g], 0, 0, 0);
        accH[1][mt][g] = __builtin_amdgcn_mfma_f32_16x16x32_bf16(a1, bq, accH[1][mt][g], 0, 0, 0);
      }
  }

  // ---------------- GRU epilogue + scatter + logits mem-part ----------------
#pragma unroll
  for (int rt = 0; rt < 2; ++rt) {
#pragma unroll
    for (int j = 0; j < 4; ++j) {
      const int rowl = rbase + rt * 16 + lk * 4 + j;   // C/D: row=(lane>>4)*4+reg
      const int grow = r0 + rowl;
      const bool valid = grow < N;
      const int gid = valid ? ids[grow] : 0;
      float lp0 = 0.f, lp1 = 0.f;
#pragma unroll
      for (int mt = 0; mt < 2; ++mt) {
        const int m = mbase + mt * 16 + lr;            // C/D: col=lane&15
        const float ir  = accI[rt][mt][0][j] + bih[m];
        const float hr  = accH[rt][mt][0][j] + bhh[m];
        const float iz  = accI[rt][mt][1][j] + bih[MEM + m];
        const float hz  = accH[rt][mt][1][j] + bhh[MEM + m];
        const float inn = accI[rt][mt][2][j] + bih[2 * MEM + m];
        const float hn  = accH[rt][mt][2][j] + bhh[2 * MEM + m];
        const float r = sigm(ir + hr);
        const float z = sigm(iz + hz);
        const float n = tanhfast(inn + r * hn);
        const float hp = bank[(size_t)gid * MEM + m];
        const float nv = (1.f - z) * n + z * hp;
        if (valid) out_bank[(size_t)gid * MEM + m] = nv;
        lp0 += nv * Wcls[EMB + m];                     // W_cls row 0, mem slice
        lp1 += nv * Wcls[(EMB + MEM) + EMB + m];       // W_cls row 1, mem slice
      }
#pragma unroll
      for (int s = 1; s < 16; s <<= 1) {
        lp0 += __shfl_xor(lp0, s);
        lp1 += __shfl_xor(lp1, s);
      }
      if (lr == 0) { sLP[w & 3][rowl][0] = lp0; sLP[w & 3][rowl][1] = lp1; }
    }
  }
  __syncthreads();

  // ---------------- logits: emb part from LDS + combine ----------------
  {
    const int row  = t >> 3;
    const int p    = t & 7;
    const int grow = r0 + row;
    float a0 = 0.f, a1 = 0.f;
#pragma unroll 2
    for (int i = 0; i < 8; ++i) {
      const int k8   = p + i * 8;
      const int byte = (row * (EMB * 2) + k8 * 16) ^ ((row & 7) << 4);
      short8 xv = *(short8*)((char*)sX + byte);
      const float* w0 = Wcls + k8 * 8;
      const float* w1 = Wcls + (EMB + MEM) + k8 * 8;
#pragma unroll
      for (int e = 0; e < 8; ++e) {
        const float x = b2f(xv[e]);
        a0 += x * w0[e];
        a1 += x * w1[e];
      }
    }
    a0 += __shfl_xor(a0, 1); a0 += __shfl_xor(a0, 2); a0 += __shfl_xor(a0, 4);
    a1 += __shfl_xor(a1, 1); a1 += __shfl_xor(a1, 2); a1 += __shfl_xor(a1, 4);
    if (p == 0 && grow < N) {
      const float m0 = sLP[0][row][0] + sLP[1][row][0] + sLP[2][row][0] + sLP[3][row][0];
      const float m1 = sLP[0][row][1] + sLP[1][row][1] + sLP[2][row][1] + sLP[3][row][1];
      out_logits[(size_t)grow * 2 + 0] = a0 + m0 + bcls[0];
      out_logits[(size_t)grow * 2 + 1] = a1 + m1 + bcls[1];
    }
  }
}

extern "C" void kernel_launch(void* const* d_in, const int* in_sizes, int n_in,
                              void* d_out, int out_size, void* d_ws, size_t ws_size,
                              hipStream_t stream) {
  const float* emb  = (const float*)d_in[0];
  const int*   ids  = (const int*)d_in[1];
  const float* bank = (const float*)d_in[2];
  const float* wih  = (const float*)d_in[3];
  const float* whh  = (const float*)d_in[4];
  const float* bih  = (const float*)d_in[5];
  const float* bhh  = (const float*)d_in[6];
  const float* wcls = (const float*)d_in[7];
  const float* bcls = (const float*)d_in[8];

  const int N          = in_sizes[1];          // number of active nodes
  const int bank_elems = in_sizes[2];          // MAX_NODES * MEM

  float* out_logits = (float*)d_out;
  float* out_bank   = (float*)d_out + (size_t)N * 2;

  // 1) copy whole bank to output (scatter overwrites active rows later)
  const int n4 = bank_elems / 4;
  copy_bank_kernel<<<8192, 256, 0, stream>>>((const f32x4*)bank, (f32x4*)out_bank, n4);

  const int nb = (N + BR - 1) / BR;
  const size_t wbytes = (size_t)(G3 * EMB + G3 * MEM) * sizeof(short);
  if (ws_size >= wbytes) {
    short* wb = (short*)d_ws;
    prep_w_kernel<<<(G3 * (EMB + MEM) + 255) / 256, 256, 0, stream>>>(wih, whh, wb);
    fused_gru_kernel<true><<<nb, NTHR, 0, stream>>>(emb, ids, bank, wih, whh, bih, bhh,
                                                    wcls, bcls, wb, wb + G3 * EMB,
                                                    out_logits, out_bank, N);
  } else {
    fused_gru_kernel<false><<<nb, NTHR, 0, stream>>>(emb, ids, bank, wih, whh, bih, bhh,
                                                     wcls, bcls, nullptr, nullptr,
                                                     out_logits, out_bank, N);
  }
}